// Round 4
// baseline (236.006 us; speedup 1.0000x reference)
//
#include <hip/hip_runtime.h>
#include <hip/hip_bf16.h>

// Spectral attention: B=2, N=50000, D=256, H=8, Dh=32, K_EIG=32, NUM_BANDS=3
// Key identity: Qf = E^T (x Wq^T + bq) = (E^T x) Wq^T + s * bq, s[k] = sum_n E[n,k]
// N-sized work: U = E^T x (read x once) and out = E @ out_freq (write out once).
// Round-3 lesson: no per-thread arrays in hot loops (scratch!), no redundant x
// reads. Wave-per-row mapping: E loads wave-uniform broadcast, x float2/lane.

constexpr int D = 256;   // d_model

#define REP32(M) M(0)M(1)M(2)M(3)M(4)M(5)M(6)M(7)M(8)M(9)M(10)M(11)M(12)M(13)M(14)M(15)M(16)M(17)M(18)M(19)M(20)M(21)M(22)M(23)M(24)M(25)M(26)M(27)M(28)M(29)M(30)M(31)

// ---------------------------------------------------------------- k_colsum
__global__ __launch_bounds__(256) void k_colsum(const float* __restrict__ E,
                                                float* __restrict__ pS, int N) {
  int k = threadIdx.x & 31;
  int rg = threadIdx.x >> 5;
  int rs = (N + 255) >> 8;
  int n0 = blockIdx.x * rs;
  int n1 = n0 + rs; if (n1 > N) n1 = N;
  float acc = 0.f;
  for (int n = n0 + rg; n < n1; n += 8) acc += E[(size_t)n * 32 + k];
  __shared__ float red[256];
  red[threadIdx.x] = acc;
  __syncthreads();
  if (threadIdx.x < 32) {
    float t = red[threadIdx.x];
#pragma unroll
    for (int i = 1; i < 8; ++i) t += red[i * 32 + threadIdx.x];
    pS[blockIdx.x * 32 + threadIdx.x] = t;
  }
}

// ---------------------------------------------------------------- k_partial
// grid = B * nchunk * 2 (d-split). 256 threads: ro = t>>6 (wave = row), dp = t&63.
// Each lane: float2 of x (no redundancy), 32 named float2 accumulators.
// E row address is wave-uniform -> broadcast loads.
__global__ __launch_bounds__(256) void k_partial(const float* __restrict__ x,
                                                 const float* __restrict__ E,
                                                 float* __restrict__ pU,
                                                 int N, int nchunk, int rpc) {
  int blk = blockIdx.x;
  int dh = blk & 1;                        // d half: 0 or 1
  int bc = blk >> 1;                       // b*nchunk + c
  int c = bc % nchunk;
  int b = bc / nchunk;
  int t = threadIdx.x;
  int ro = t >> 6;                         // 0..3 (one wave per row)
  int dp = t & 63;
  int dfull = dh * 128 + 2 * dp;
  int n0 = c * rpc;
  int n1 = n0 + rpc; if (n1 > N) n1 = N;

#define DECL(i) float2 c##i = {0.f, 0.f};
  REP32(DECL)
#undef DECL

  const float* xb = x + (size_t)b * N * D + dfull;
  const float4* E4 = reinterpret_cast<const float4*>(E);

#define FMA_G(e, cA, cB, cC, cD)                                   \
  cA.x = fmaf(e.x, xv.x, cA.x); cA.y = fmaf(e.x, xv.y, cA.y);      \
  cB.x = fmaf(e.y, xv.x, cB.x); cB.y = fmaf(e.y, xv.y, cB.y);      \
  cC.x = fmaf(e.z, xv.x, cC.x); cC.y = fmaf(e.z, xv.y, cC.y);      \
  cD.x = fmaf(e.w, xv.x, cD.x); cD.y = fmaf(e.w, xv.y, cD.y);

  for (int n = n0; n < n1; n += 4) {
    int row = n + ro;
    if (row < n1) {
      float2 xv = *reinterpret_cast<const float2*>(xb + (size_t)row * D);
      const float4* Er = E4 + (size_t)row * 8;
      float4 e0 = Er[0], e1 = Er[1], e2 = Er[2], e3 = Er[3];
      float4 e4 = Er[4], e5 = Er[5], e6 = Er[6], e7 = Er[7];
      FMA_G(e0, c0,  c1,  c2,  c3)
      FMA_G(e1, c4,  c5,  c6,  c7)
      FMA_G(e2, c8,  c9,  c10, c11)
      FMA_G(e3, c12, c13, c14, c15)
      FMA_G(e4, c16, c17, c18, c19)
      FMA_G(e5, c20, c21, c22, c23)
      FMA_G(e6, c24, c25, c26, c27)
      FMA_G(e7, c28, c29, c30, c31)
    }
  }
#undef FMA_G

  // cross-wave reduce: 4 waves hold partial sums for the same (k, d) pair
  __shared__ float redbuf[4][32][128];     // [ro][k][d-pair*2] 64KB? no: 4*32*128*4B = 64KB too big
  // NOTE: instead reduce via LDS in two steps using 16KB at a time is complex;
  // simpler: each wave writes its own partial rows and k_reduce sums 4x more.
  float* o = pU + ((size_t)(b * nchunk + c) * 4 + ro) * 8192 + dfull;
#define STO(i) *reinterpret_cast<float2*>(o + (i) * 256) = c##i;
  REP32(STO)
#undef STO
}

// ---------------------------------------------------------------- k_reduce
// U[b,kd] = sum over (nchunk*4) partials
__global__ __launch_bounds__(256) void k_reduce(const float* __restrict__ pU,
                                                float* __restrict__ U, int nparts) {
  int e = blockIdx.x * 64 + (threadIdx.x & 63);
  int sub = threadIdx.x >> 6;              // 0..3
  int b = e >> 13;
  int kd = e & 8191;
  const float* p = pU + (size_t)b * nparts * 8192 + kd;
  float acc = 0.f;
  for (int c = sub; c < nparts; c += 4) acc += p[(size_t)c * 8192];
  __shared__ float red[256];
  red[threadIdx.x] = acc;
  __syncthreads();
  if (threadIdx.x < 64)
    U[e] = (red[threadIdx.x] + red[threadIdx.x + 64]) +
           (red[threadIdx.x + 128] + red[threadIdx.x + 192]);
}

// ---------------------------------------------------------------- k_project
__global__ __launch_bounds__(256) void k_project(
    const float* __restrict__ U, const float* __restrict__ pS,
    const float* __restrict__ Wq, const float* __restrict__ bq,
    const float* __restrict__ Wk, const float* __restrict__ bk,
    const float* __restrict__ Wv, const float* __restrict__ bv,
    const float* __restrict__ ev, const float* __restrict__ bb,
    const float* __restrict__ fw,
    float* __restrict__ Qfg, float* __restrict__ Kfg, float* __restrict__ Vfg) {
  int blk = blockIdx.x;                    // b*32 + k
  int k = blk & 31;
  int t = threadIdx.x;
  __shared__ __align__(16) float u[256];
  __shared__ float red[256];
  u[t] = U[(size_t)blk * 256 + t];
  red[t] = pS[t * 32 + k];
  __syncthreads();
#pragma unroll
  for (int off = 128; off > 0; off >>= 1) {
    if (t < off) red[t] += red[t + off];
    __syncthreads();
  }
  float sk = red[0];

  // filter response — FP64 to match numpy ref branch semantics
  float mnf = ev[0], mxf = ev[0];
#pragma unroll
  for (int i = 1; i < 32; ++i) { float v = ev[i]; mnf = fminf(mnf, v); mxf = fmaxf(mxf, v); }
  double mn = (double)mnf, mx = (double)mxf;
  double lam = ((double)ev[k] - mn) / (mx - mn + 1e-8);
  int h = t >> 5;
  float g = 0.f;
#pragma unroll
  for (int i = 0; i < 3; ++i) {
    double lo = (double)bb[h * 4 + i], hi = (double)bb[h * 4 + i + 1];
    if (lam >= lo && lam < hi) g = fw[(h * 3 + i) * 32 + k];
  }

  const float4* u4 = reinterpret_cast<const float4*>(u);
  const float4* wq4 = reinterpret_cast<const float4*>(Wq) + (size_t)t * 64;
  const float4* wk4 = reinterpret_cast<const float4*>(Wk) + (size_t)t * 64;
  const float4* wv4 = reinterpret_cast<const float4*>(Wv) + (size_t)t * 64;
  float aq = 0.f, ak = 0.f, av = 0.f;
#pragma unroll 4
  for (int j = 0; j < 64; ++j) {
    float4 uv = u4[j];
    float4 q = wq4[j], kk = wk4[j], vv = wv4[j];
    aq = fmaf(uv.x, q.x, aq);  aq = fmaf(uv.y, q.y, aq);
    aq = fmaf(uv.z, q.z, aq);  aq = fmaf(uv.w, q.w, aq);
    ak = fmaf(uv.x, kk.x, ak); ak = fmaf(uv.y, kk.y, ak);
    ak = fmaf(uv.z, kk.z, ak); ak = fmaf(uv.w, kk.w, ak);
    av = fmaf(uv.x, vv.x, av); av = fmaf(uv.y, vv.y, av);
    av = fmaf(uv.z, vv.z, av); av = fmaf(uv.w, vv.w, av);
  }
  Qfg[(size_t)blk * 256 + t] = (aq + bq[t] * sk) * g;
  Kfg[(size_t)blk * 256 + t] = (ak + bk[t] * sk) * g;
  Vfg[(size_t)blk * 256 + t] = (av + bv[t] * sk) * g;
}

// ---------------------------------------------------------------- k_attn
__global__ __launch_bounds__(1024) void k_attn(const float* __restrict__ Qfg,
                                               const float* __restrict__ Kfg,
                                               const float* __restrict__ Vfg,
                                               float* __restrict__ of) {
  int blk = blockIdx.x;                    // b*8 + h
  int b = blk >> 3, h = blk & 7;
  int tid = threadIdx.x;
  int row = tid >> 5, col = tid & 31;
  __shared__ float Q[32][33], Kt[32][33], V[32][33], A[32][33];
  size_t base = (size_t)b * 32 * 256 + h * 32;
  Q[row][col]  = Qfg[base + row * 256 + col];
  Kt[row][col] = Kfg[base + row * 256 + col];
  V[row][col]  = Vfg[base + row * 256 + col];
  __syncthreads();
  float sc = 0.f;
#pragma unroll
  for (int d0 = 0; d0 < 32; ++d0) sc = fmaf(Q[row][d0], Kt[col][d0], sc);
  sc *= 0.17677669529663687f;              // 1/sqrt(32)
  float m = sc;
#pragma unroll
  for (int o = 16; o > 0; o >>= 1) m = fmaxf(m, __shfl_xor(m, o, 32));
  float p = expf(sc - m);
  float su = p;
#pragma unroll
  for (int o = 16; o > 0; o >>= 1) su += __shfl_xor(su, o, 32);
  A[row][col] = p / su;
  __syncthreads();
  float o_ = 0.f;
#pragma unroll
  for (int l = 0; l < 32; ++l) o_ = fmaf(A[row][l], V[l][col], o_);
  of[base + row * 256 + col] = o_;
}

// ---------------------------------------------------------------- k_expand
// out[b,n,d] = sum_k E[n,k] * of[b,k,d]. grid = B * nbr * 2 (d-split).
// 256 threads: ro = t>>6 (wave = row), dp = t&63, float2 of d per lane.
// of-slice held in 32 named float2 registers; E loads wave-uniform broadcast.
__global__ __launch_bounds__(256) void k_expand(const float* __restrict__ E,
                                                const float* __restrict__ of,
                                                float* __restrict__ out,
                                                int N, int nbr, int rows) {
  int blk = blockIdx.x;
  int dh = blk & 1;
  int t2 = blk >> 1;
  int b = t2 / nbr;
  int br = t2 % nbr;
  int t = threadIdx.x;
  int ro = t >> 6;
  int dp = t & 63;
  int dfull = dh * 128 + 2 * dp;

  const float* ofb = of + (size_t)b * 8192 + dfull;
#define LDF(i) float2 f##i = *reinterpret_cast<const float2*>(ofb + (i) * 256);
  REP32(LDF)
#undef LDF

  int n0 = br * rows;
  int n1 = n0 + rows; if (n1 > N) n1 = N;
  const float4* E4 = reinterpret_cast<const float4*>(E);
  float* ob = out + (size_t)b * N * D + dfull;

#define EXP_G(e, fA, fB, fC, fD)                                   \
  o2.x = fmaf(e.x, fA.x, o2.x); o2.y = fmaf(e.x, fA.y, o2.y);      \
  o2.x = fmaf(e.y, fB.x, o2.x); o2.y = fmaf(e.y, fB.y, o2.y);      \
  o2.x = fmaf(e.z, fC.x, o2.x); o2.y = fmaf(e.z, fC.y, o2.y);      \
  o2.x = fmaf(e.w, fD.x, o2.x); o2.y = fmaf(e.w, fD.y, o2.y);

  for (int n = n0; n < n1; n += 4) {
    int row = n + ro;
    if (row < n1) {
      const float4* Er = E4 + (size_t)row * 8;
      float4 e0 = Er[0], e1 = Er[1], e2 = Er[2], e3 = Er[3];
      float4 e4 = Er[4], e5 = Er[5], e6 = Er[6], e7 = Er[7];
      float2 o2 = {0.f, 0.f};
      EXP_G(e0, f0,  f1,  f2,  f3)
      EXP_G(e1, f4,  f5,  f6,  f7)
      EXP_G(e2, f8,  f9,  f10, f11)
      EXP_G(e3, f12, f13, f14, f15)
      EXP_G(e4, f16, f17, f18, f19)
      EXP_G(e5, f20, f21, f22, f23)
      EXP_G(e6, f24, f25, f26, f27)
      EXP_G(e7, f28, f29, f30, f31)
      *reinterpret_cast<float2*>(ob + (size_t)row * D) = o2;
    }
  }
#undef EXP_G
}

// ---------------------------------------------------------------- launch
extern "C" void kernel_launch(void* const* d_in, const int* in_sizes, int n_in,
                              void* d_out, int out_size, void* d_ws, size_t ws_size,
                              hipStream_t stream) {
  const float* x  = (const float*)d_in[0];
  const float* E  = (const float*)d_in[1];
  const float* ev = (const float*)d_in[2];
  const float* Wq = (const float*)d_in[3];
  const float* bq = (const float*)d_in[4];
  const float* Wk = (const float*)d_in[5];
  const float* bk = (const float*)d_in[6];
  const float* Wv = (const float*)d_in[7];
  const float* bv = (const float*)d_in[8];
  const float* bb = (const float*)d_in[9];
  const float* fw = (const float*)d_in[10];
  float* out = (float*)d_out;
  float* ws  = (float*)d_ws;

  const int N = in_sizes[1] / 32;          // 50000
  const int B = in_sizes[0] / (N * 256);   // 2

  // workspace layout (floats)
  float* U   = ws;                         // B*32*256 = 16384
  float* Qfg = ws + 16384;
  float* Kfg = ws + 32768;
  float* Vfg = ws + 49152;
  float* of  = ws + 65536;
  float* pS  = ws + 81920;                 // 256*32 = 8192
  float* pU  = ws + 90112;                 // B*nchunk*4*8192 floats

  int nchunk = 64;
  while (nchunk > 8 &&
         (90112 + (size_t)B * nchunk * 4 * 8192) * sizeof(float) > ws_size)
    nchunk >>= 1;
  int rpc = (N + nchunk - 1) / nchunk;
  int nparts = nchunk * 4;                 // 4 waves write separate partials

  k_colsum<<<256, 256, 0, stream>>>(E, pS, N);
  k_partial<<<B * nchunk * 2, 256, 0, stream>>>(x, E, pU, N, nchunk, rpc);
  k_reduce<<<B * 128, 256, 0, stream>>>(pU, U, nparts);
  k_project<<<B * 32, 256, 0, stream>>>(U, pS, Wq, bq, Wk, bk, Wv, bv,
                                        ev, bb, fw, Qfg, Kfg, Vfg);
  k_attn<<<B * 8, 1024, 0, stream>>>(Qfg, Kfg, Vfg, of);
  int rows = 128;
  int nbr = (N + rows - 1) / rows;
  k_expand<<<B * nbr * 2, 256, 0, stream>>>(E, of, out, N, nbr, rows);
}

// Round 5
// 230.861 us; speedup vs baseline: 1.0223x; 1.0223x over previous
//
#include <hip/hip_runtime.h>
#include <hip/hip_bf16.h>

// Spectral attention: B=2, N=50000, D=256, H=8, Dh=32, K_EIG=32, NUM_BANDS=3
// Key identity: Qf = E^T (x Wq^T + bq) = (E^T x) Wq^T + s * bq, s[k] = sum_n E[n,k]
// N-sized work: U = E^T x (read x once) and out = E @ out_freq (write out once).
// Lessons: r2 = per-thread arrays spill to scratch (use named regs);
// r3 = don't read x redundantly; r4 = grid must be >= 4 blocks/CU (1024 blocks).

constexpr int D = 256;   // d_model

// ---------------------------------------------------------------- k_colsum
__global__ __launch_bounds__(256) void k_colsum(const float* __restrict__ E,
                                                float* __restrict__ pS, int N) {
  int k = threadIdx.x & 31;
  int rg = threadIdx.x >> 5;
  int rs = (N + 255) >> 8;
  int n0 = blockIdx.x * rs;
  int n1 = n0 + rs; if (n1 > N) n1 = N;
  float acc = 0.f;
  for (int n = n0 + rg; n < n1; n += 8) acc += E[(size_t)n * 32 + k];
  __shared__ float red[256];
  red[threadIdx.x] = acc;
  __syncthreads();
  if (threadIdx.x < 32) {
    float t = red[threadIdx.x];
#pragma unroll
    for (int i = 1; i < 8; ++i) t += red[i * 32 + threadIdx.x];
    pS[blockIdx.x * 32 + threadIdx.x] = t;
  }
}

// ---------------------------------------------------------------- k_partial
// grid = B*nchunk*2 (d-half split), 256 thr: ro = wave = row offset, dp = d-pair.
// Named float2 accumulators (no scratch), x software-pipelined 2 rows ahead,
// E loads wave-uniform broadcast. Cross-wave LDS reduce -> one 16KB partial/block.
__global__ __launch_bounds__(256) void k_partial(const float* __restrict__ x,
                                                 const float* __restrict__ E,
                                                 float* __restrict__ pU,
                                                 int N, int nchunk, int rpc) {
  int blk = blockIdx.x;
  int dh = blk & 1;                        // d half: 0 or 1
  int bc = blk >> 1;                       // b*nchunk + c
  int c = bc % nchunk;
  int b = bc / nchunk;
  int t = threadIdx.x;
  int ro = t >> 6;                         // 0..3 (one wave per row phase)
  int dp = t & 63;
  int dfull = dh * 128 + 2 * dp;
  int n0 = c * rpc;
  int n1 = n0 + rpc; if (n1 > N) n1 = N;

  float2 c0={0,0},c1={0,0},c2={0,0},c3={0,0},c4={0,0},c5={0,0},c6={0,0},c7={0,0};
  float2 c8={0,0},c9={0,0},c10={0,0},c11={0,0},c12={0,0},c13={0,0},c14={0,0},c15={0,0};
  float2 c16={0,0},c17={0,0},c18={0,0},c19={0,0},c20={0,0},c21={0,0},c22={0,0},c23={0,0};
  float2 c24={0,0},c25={0,0},c26={0,0},c27={0,0},c28={0,0},c29={0,0},c30={0,0},c31={0,0};

  const float* xb = x + (size_t)b * N * D + dfull;
  const float4* E4 = reinterpret_cast<const float4*>(E);

  // x pipeline: 2 rows in flight
  int r0 = n0 + ro;
  float2 xv0 = {0,0}, xv1 = {0,0};
  if (r0 < n1)     xv0 = *reinterpret_cast<const float2*>(xb + (size_t)r0 * D);
  if (r0 + 4 < n1) xv1 = *reinterpret_cast<const float2*>(xb + (size_t)(r0 + 4) * D);

#define FMA_G(e, cA, cB, cC, cD)                                   \
  cA.x = fmaf(e.x, xv.x, cA.x); cA.y = fmaf(e.x, xv.y, cA.y);      \
  cB.x = fmaf(e.y, xv.x, cB.x); cB.y = fmaf(e.y, xv.y, cB.y);      \
  cC.x = fmaf(e.z, xv.x, cC.x); cC.y = fmaf(e.z, xv.y, cC.y);      \
  cD.x = fmaf(e.w, xv.x, cD.x); cD.y = fmaf(e.w, xv.y, cD.y);

  for (int n = r0; n < n1; n += 4) {
    float2 xv = xv0;
    xv0 = xv1;
    int rn = n + 8;
    xv1 = (rn < n1) ? *reinterpret_cast<const float2*>(xb + (size_t)rn * D)
                    : make_float2(0.f, 0.f);
    const float4* Er = E4 + (size_t)n * 8;
    float4 e0 = Er[0], e1 = Er[1], e2 = Er[2], e3 = Er[3];
    float4 e4 = Er[4], e5 = Er[5], e6 = Er[6], e7 = Er[7];
    FMA_G(e0, c0,  c1,  c2,  c3)
    FMA_G(e1, c4,  c5,  c6,  c7)
    FMA_G(e2, c8,  c9,  c10, c11)
    FMA_G(e3, c12, c13, c14, c15)
    FMA_G(e4, c16, c17, c18, c19)
    FMA_G(e5, c20, c21, c22, c23)
    FMA_G(e6, c24, c25, c26, c27)
    FMA_G(e7, c28, c29, c30, c31)
  }
#undef FMA_G

  // cross-wave reduction, one k-octet at a time (LDS 16KB, float2, 2-way free)
  __shared__ float2 lred[4][8][64];
  float* o = pU + ((size_t)bc * 2 + dh) * 4096;   // [32][128] partial

#define OCTET(g, cA, cB, cC, cD, cE, cF, cG, cH)                   \
  {                                                                \
    lred[ro][0][dp] = cA; lred[ro][1][dp] = cB;                    \
    lred[ro][2][dp] = cC; lred[ro][3][dp] = cD;                    \
    lred[ro][4][dp] = cE; lred[ro][5][dp] = cF;                    \
    lred[ro][6][dp] = cG; lred[ro][7][dp] = cH;                    \
    __syncthreads();                                               \
    _Pragma("unroll")                                              \
    for (int i = 0; i < 2; ++i) {                                  \
      int idx = i * 256 + t;                                       \
      int kk = idx >> 6, dpp = idx & 63;                           \
      float2 s0 = lred[0][kk][dpp], s1 = lred[1][kk][dpp];         \
      float2 s2 = lred[2][kk][dpp], s3 = lred[3][kk][dpp];         \
      float2 sv;                                                   \
      sv.x = (s0.x + s1.x) + (s2.x + s3.x);                        \
      sv.y = (s0.y + s1.y) + (s2.y + s3.y);                        \
      *reinterpret_cast<float2*>(o + ((g) * 8 + kk) * 128 + 2 * dpp) = sv; \
    }                                                              \
    __syncthreads();                                               \
  }

  OCTET(0, c0,  c1,  c2,  c3,  c4,  c5,  c6,  c7)
  OCTET(1, c8,  c9,  c10, c11, c12, c13, c14, c15)
  OCTET(2, c16, c17, c18, c19, c20, c21, c22, c23)
  OCTET(3, c24, c25, c26, c27, c28, c29, c30, c31)
#undef OCTET
}

// ---------------------------------------------------------------- k_reduce
// U[b, k, d] = sum_c pU[(b*nchunk+c)*2 + dh][k][dl]
__global__ __launch_bounds__(256) void k_reduce(const float* __restrict__ pU,
                                                float* __restrict__ U, int nchunk) {
  int e = blockIdx.x * 64 + (threadIdx.x & 63);   // global (b,k,d) element
  int sub = threadIdx.x >> 6;                     // 0..3
  int b = e >> 13;
  int kd = e & 8191;
  int k = kd >> 8;
  int d = kd & 255;
  int dh = d >> 7, dl = d & 127;
  const float* p = pU + ((size_t)(b * nchunk) * 2 + dh) * 4096 + k * 128 + dl;
  float acc = 0.f;
  for (int c = sub; c < nchunk; c += 4) acc += p[(size_t)c * 8192];
  __shared__ float red[256];
  red[threadIdx.x] = acc;
  __syncthreads();
  if (threadIdx.x < 64)
    U[e] = (red[threadIdx.x] + red[threadIdx.x + 64]) +
           (red[threadIdx.x + 128] + red[threadIdx.x + 192]);
}

// ---------------------------------------------------------------- k_project
__global__ __launch_bounds__(256) void k_project(
    const float* __restrict__ U, const float* __restrict__ pS,
    const float* __restrict__ Wq, const float* __restrict__ bq,
    const float* __restrict__ Wk, const float* __restrict__ bk,
    const float* __restrict__ Wv, const float* __restrict__ bv,
    const float* __restrict__ ev, const float* __restrict__ bb,
    const float* __restrict__ fw,
    float* __restrict__ Qfg, float* __restrict__ Kfg, float* __restrict__ Vfg) {
  int blk = blockIdx.x;                    // b*32 + k
  int k = blk & 31;
  int t = threadIdx.x;
  __shared__ __align__(16) float u[256];
  __shared__ float red[256];
  u[t] = U[(size_t)blk * 256 + t];
  red[t] = pS[t * 32 + k];
  __syncthreads();
#pragma unroll
  for (int off = 128; off > 0; off >>= 1) {
    if (t < off) red[t] += red[t + off];
    __syncthreads();
  }
  float sk = red[0];

  // filter response — FP64 to match numpy ref branch semantics
  float mnf = ev[0], mxf = ev[0];
#pragma unroll
  for (int i = 1; i < 32; ++i) { float v = ev[i]; mnf = fminf(mnf, v); mxf = fmaxf(mxf, v); }
  double mn = (double)mnf, mx = (double)mxf;
  double lam = ((double)ev[k] - mn) / (mx - mn + 1e-8);
  int h = t >> 5;
  float g = 0.f;
#pragma unroll
  for (int i = 0; i < 3; ++i) {
    double lo = (double)bb[h * 4 + i], hi = (double)bb[h * 4 + i + 1];
    if (lam >= lo && lam < hi) g = fw[(h * 3 + i) * 32 + k];
  }

  const float4* u4 = reinterpret_cast<const float4*>(u);
  const float4* wq4 = reinterpret_cast<const float4*>(Wq) + (size_t)t * 64;
  const float4* wk4 = reinterpret_cast<const float4*>(Wk) + (size_t)t * 64;
  const float4* wv4 = reinterpret_cast<const float4*>(Wv) + (size_t)t * 64;
  float aq = 0.f, ak = 0.f, av = 0.f;
#pragma unroll 4
  for (int j = 0; j < 64; ++j) {
    float4 uv = u4[j];
    float4 q = wq4[j], kk = wk4[j], vv = wv4[j];
    aq = fmaf(uv.x, q.x, aq);  aq = fmaf(uv.y, q.y, aq);
    aq = fmaf(uv.z, q.z, aq);  aq = fmaf(uv.w, q.w, aq);
    ak = fmaf(uv.x, kk.x, ak); ak = fmaf(uv.y, kk.y, ak);
    ak = fmaf(uv.z, kk.z, ak); ak = fmaf(uv.w, kk.w, ak);
    av = fmaf(uv.x, vv.x, av); av = fmaf(uv.y, vv.y, av);
    av = fmaf(uv.z, vv.z, av); av = fmaf(uv.w, vv.w, av);
  }
  Qfg[(size_t)blk * 256 + t] = (aq + bq[t] * sk) * g;
  Kfg[(size_t)blk * 256 + t] = (ak + bk[t] * sk) * g;
  Vfg[(size_t)blk * 256 + t] = (av + bv[t] * sk) * g;
}

// ---------------------------------------------------------------- k_attn
__global__ __launch_bounds__(1024) void k_attn(const float* __restrict__ Qfg,
                                               const float* __restrict__ Kfg,
                                               const float* __restrict__ Vfg,
                                               float* __restrict__ of) {
  int blk = blockIdx.x;                    // b*8 + h
  int b = blk >> 3, h = blk & 7;
  int tid = threadIdx.x;
  int row = tid >> 5, col = tid & 31;
  __shared__ float Q[32][33], Kt[32][33], V[32][33], A[32][33];
  size_t base = (size_t)b * 32 * 256 + h * 32;
  Q[row][col]  = Qfg[base + row * 256 + col];
  Kt[row][col] = Kfg[base + row * 256 + col];
  V[row][col]  = Vfg[base + row * 256 + col];
  __syncthreads();
  float sc = 0.f;
#pragma unroll
  for (int d0 = 0; d0 < 32; ++d0) sc = fmaf(Q[row][d0], Kt[col][d0], sc);
  sc *= 0.17677669529663687f;              // 1/sqrt(32)
  float m = sc;
#pragma unroll
  for (int o = 16; o > 0; o >>= 1) m = fmaxf(m, __shfl_xor(m, o, 32));
  float p = expf(sc - m);
  float su = p;
#pragma unroll
  for (int o = 16; o > 0; o >>= 1) su += __shfl_xor(su, o, 32);
  A[row][col] = p / su;
  __syncthreads();
  float o_ = 0.f;
#pragma unroll
  for (int l = 0; l < 32; ++l) o_ = fmaf(A[row][l], V[l][col], o_);
  of[base + row * 256 + col] = o_;
}

// ---------------------------------------------------------------- k_expand
// out[b,n,d] = sum_k E[n,k] * of[b,k,d]; named regs, E wave-uniform broadcast
__global__ __launch_bounds__(256) void k_expand(const float* __restrict__ E,
                                                const float* __restrict__ of,
                                                float* __restrict__ out,
                                                int N, int nbr, int rows) {
  int blk = blockIdx.x;
  int dh = blk & 1;
  int t2 = blk >> 1;
  int b = t2 / nbr;
  int br = t2 % nbr;
  int t = threadIdx.x;
  int ro = t >> 6;
  int dp = t & 63;
  int dfull = dh * 128 + 2 * dp;

  const float* ofb = of + (size_t)b * 8192 + dfull;
  float2 f0  = *(const float2*)(ofb +  0*256), f1  = *(const float2*)(ofb +  1*256);
  float2 f2  = *(const float2*)(ofb +  2*256), f3  = *(const float2*)(ofb +  3*256);
  float2 f4  = *(const float2*)(ofb +  4*256), f5  = *(const float2*)(ofb +  5*256);
  float2 f6  = *(const float2*)(ofb +  6*256), f7  = *(const float2*)(ofb +  7*256);
  float2 f8  = *(const float2*)(ofb +  8*256), f9  = *(const float2*)(ofb +  9*256);
  float2 f10 = *(const float2*)(ofb + 10*256), f11 = *(const float2*)(ofb + 11*256);
  float2 f12 = *(const float2*)(ofb + 12*256), f13 = *(const float2*)(ofb + 13*256);
  float2 f14 = *(const float2*)(ofb + 14*256), f15 = *(const float2*)(ofb + 15*256);
  float2 f16 = *(const float2*)(ofb + 16*256), f17 = *(const float2*)(ofb + 17*256);
  float2 f18 = *(const float2*)(ofb + 18*256), f19 = *(const float2*)(ofb + 19*256);
  float2 f20 = *(const float2*)(ofb + 20*256), f21 = *(const float2*)(ofb + 21*256);
  float2 f22 = *(const float2*)(ofb + 22*256), f23 = *(const float2*)(ofb + 23*256);
  float2 f24 = *(const float2*)(ofb + 24*256), f25 = *(const float2*)(ofb + 25*256);
  float2 f26 = *(const float2*)(ofb + 26*256), f27 = *(const float2*)(ofb + 27*256);
  float2 f28 = *(const float2*)(ofb + 28*256), f29 = *(const float2*)(ofb + 29*256);
  float2 f30 = *(const float2*)(ofb + 30*256), f31 = *(const float2*)(ofb + 31*256);

  int n0 = br * rows;
  int n1 = n0 + rows; if (n1 > N) n1 = N;
  const float4* E4 = reinterpret_cast<const float4*>(E);
  float* ob = out + (size_t)b * N * D + dfull;

#define EXP_G(e, fA, fB, fC, fD)                                   \
  o2.x = fmaf(e.x, fA.x, o2.x); o2.y = fmaf(e.x, fA.y, o2.y);      \
  o2.x = fmaf(e.y, fB.x, o2.x); o2.y = fmaf(e.y, fB.y, o2.y);      \
  o2.x = fmaf(e.z, fC.x, o2.x); o2.y = fmaf(e.z, fC.y, o2.y);      \
  o2.x = fmaf(e.w, fD.x, o2.x); o2.y = fmaf(e.w, fD.y, o2.y);

  for (int n = n0 + ro; n < n1; n += 4) {
    const float4* Er = E4 + (size_t)n * 8;
    float4 e0 = Er[0], e1 = Er[1], e2 = Er[2], e3 = Er[3];
    float4 e4 = Er[4], e5 = Er[5], e6 = Er[6], e7 = Er[7];
    float2 o2 = {0.f, 0.f};
    EXP_G(e0, f0,  f1,  f2,  f3)
    EXP_G(e1, f4,  f5,  f6,  f7)
    EXP_G(e2, f8,  f9,  f10, f11)
    EXP_G(e3, f12, f13, f14, f15)
    EXP_G(e4, f16, f17, f18, f19)
    EXP_G(e5, f20, f21, f22, f23)
    EXP_G(e6, f24, f25, f26, f27)
    EXP_G(e7, f28, f29, f30, f31)
    *reinterpret_cast<float2*>(ob + (size_t)n * D) = o2;
  }
#undef EXP_G
}

// ---------------------------------------------------------------- launch
extern "C" void kernel_launch(void* const* d_in, const int* in_sizes, int n_in,
                              void* d_out, int out_size, void* d_ws, size_t ws_size,
                              hipStream_t stream) {
  const float* x  = (const float*)d_in[0];
  const float* E  = (const float*)d_in[1];
  const float* ev = (const float*)d_in[2];
  const float* Wq = (const float*)d_in[3];
  const float* bq = (const float*)d_in[4];
  const float* Wk = (const float*)d_in[5];
  const float* bk = (const float*)d_in[6];
  const float* Wv = (const float*)d_in[7];
  const float* bv = (const float*)d_in[8];
  const float* bb = (const float*)d_in[9];
  const float* fw = (const float*)d_in[10];
  float* out = (float*)d_out;
  float* ws  = (float*)d_ws;

  const int N = in_sizes[1] / 32;          // 50000
  const int B = in_sizes[0] / (N * 256);   // 2

  // workspace layout (floats)
  float* U   = ws;                         // B*32*256 = 16384
  float* Qfg = ws + 16384;
  float* Kfg = ws + 32768;
  float* Vfg = ws + 49152;
  float* of  = ws + 65536;
  float* pS  = ws + 81920;                 // 256*32 = 8192
  float* pU  = ws + 90112;                 // B*nchunk*2*4096 floats

  int nchunk = 256;                        // grid = B*nchunk*2 = 1024 blocks
  while (nchunk > 32 &&
         (90112 + (size_t)B * nchunk * 8192) * sizeof(float) > ws_size)
    nchunk >>= 1;
  int rpc = (N + nchunk - 1) / nchunk;

  k_colsum<<<256, 256, 0, stream>>>(E, pS, N);
  k_partial<<<B * nchunk * 2, 256, 0, stream>>>(x, E, pU, N, nchunk, rpc);
  k_reduce<<<B * 128, 256, 0, stream>>>(pU, U, nchunk);
  k_project<<<B * 32, 256, 0, stream>>>(U, pS, Wq, bq, Wk, bk, Wv, bv,
                                        ev, bb, fw, Qfg, Kfg, Vfg);
  k_attn<<<B * 8, 1024, 0, stream>>>(Qfg, Kfg, Vfg, of);
  int rows = 128;
  int nbr = (N + rows - 1) / rows;
  k_expand<<<B * nbr * 2, 256, 0, stream>>>(E, of, out, N, nbr, rows);
}

// Round 6
// 144.833 us; speedup vs baseline: 1.6295x; 1.5940x over previous
//
#include <hip/hip_runtime.h>
#include <hip/hip_bf16.h>

// Spectral attention: B=2, N=50000, D=256, H=8, Dh=32, K_EIG=32, NUM_BANDS=3
// Key identity: Qf = E^T (x Wq^T + bq) = (E^T x) Wq^T + s * bq, s[k] = sum_n E[n,k]
// N-sized work: U = E^T x (read x once) and out = E @ out_freq (write out once).
// Lessons: r2 = per-thread arrays spill to scratch (named regs only);
// r3 = don't read x redundantly from HBM; r4 = grid >= 4 blocks/CU;
// r5 = E loads in the inner loop were latency-exposed -> stage E in LDS,
//      keep VGPR low enough for >=4 waves/SIMD.

constexpr int D = 256;   // d_model

// ---------------------------------------------------------------- k_colsum
__global__ __launch_bounds__(256) void k_colsum(const float* __restrict__ E,
                                                float* __restrict__ pS, int N) {
  int k = threadIdx.x & 31;
  int rg = threadIdx.x >> 5;
  int rs = (N + 255) >> 8;
  int n0 = blockIdx.x * rs;
  int n1 = n0 + rs; if (n1 > N) n1 = N;
  float acc = 0.f;
  for (int n = n0 + rg; n < n1; n += 8) acc += E[(size_t)n * 32 + k];
  __shared__ float red[256];
  red[threadIdx.x] = acc;
  __syncthreads();
  if (threadIdx.x < 32) {
    float t = red[threadIdx.x];
#pragma unroll
    for (int i = 1; i < 8; ++i) t += red[i * 32 + threadIdx.x];
    pS[blockIdx.x * 32 + threadIdx.x] = t;
  }
}

// ---------------------------------------------------------------- k_partial
// grid = B*nchunk. 4 waves/block; wave w owns k-octet [8w,8w+8); lane owns
// d-quad 4*lane (float4 x loads, 16B/lane). E tile staged in LDS, read via
// broadcast ds_read. 8 float4 accumulators (named) -> ~70 VGPR.
// pU[b*nchunk+c][k][d] = sum_{n in chunk} E[n,k] * x[b,n,d]
__global__ __launch_bounds__(256) void k_partial(const float* __restrict__ x,
                                                 const float* __restrict__ E,
                                                 float* __restrict__ pU,
                                                 int N, int nchunk, int rpc) {
  int blk = blockIdx.x;                    // b*nchunk + c
  int c = blk % nchunk;
  int b = blk / nchunk;
  int t = threadIdx.x;
  int w = t >> 6;                          // wave id 0..3 -> k-octet
  int lane = t & 63;
  int n0 = c * rpc;
  int n1 = n0 + rpc; if (n1 > N) n1 = N;
  int nrows = n1 - n0;

  // stage E tile [nrows][32] -> LDS (rpc <= 196 guaranteed by launcher)
  __shared__ __align__(16) float Elds[196 * 32];
  {
    const float4* Esrc = reinterpret_cast<const float4*>(E + (size_t)n0 * 32);
    float4* Edst = reinterpret_cast<float4*>(Elds);
    int nf4 = nrows * 8;
    for (int i = t; i < nf4; i += 256) Edst[i] = Esrc[i];
  }
  __syncthreads();

  float4 a0 = {0,0,0,0}, a1 = {0,0,0,0}, a2 = {0,0,0,0}, a3 = {0,0,0,0};
  float4 a4 = {0,0,0,0}, a5 = {0,0,0,0}, a6 = {0,0,0,0}, a7 = {0,0,0,0};

  const float* xb = x + (size_t)b * N * D + 4 * lane;

  // 2-deep x pipeline
  float4 xp0 = {0,0,0,0}, xp1 = {0,0,0,0};
  if (nrows > 0) xp0 = *reinterpret_cast<const float4*>(xb + (size_t)n0 * D);
  if (nrows > 1) xp1 = *reinterpret_cast<const float4*>(xb + (size_t)(n0 + 1) * D);

#define FMA4(s, v) { a##v.x = fmaf(s, xq.x, a##v.x); a##v.y = fmaf(s, xq.y, a##v.y); \
                     a##v.z = fmaf(s, xq.z, a##v.z); a##v.w = fmaf(s, xq.w, a##v.w); }
  for (int i = 0; i < nrows; ++i) {
    float4 xq = xp0;
    xp0 = xp1;
    if (i + 2 < nrows)
      xp1 = *reinterpret_cast<const float4*>(xb + (size_t)(n0 + i + 2) * D);
    const float4* er = reinterpret_cast<const float4*>(Elds + i * 32 + 8 * w);
    float4 e0 = er[0], e1 = er[1];
    FMA4(e0.x, 0) FMA4(e0.y, 1) FMA4(e0.z, 2) FMA4(e0.w, 3)
    FMA4(e1.x, 4) FMA4(e1.y, 5) FMA4(e1.z, 6) FMA4(e1.w, 7)
  }
#undef FMA4

  float* o = pU + (size_t)blk * 8192 + (size_t)(8 * w) * 256 + 4 * lane;
  *reinterpret_cast<float4*>(o + 0 * 256) = a0;
  *reinterpret_cast<float4*>(o + 1 * 256) = a1;
  *reinterpret_cast<float4*>(o + 2 * 256) = a2;
  *reinterpret_cast<float4*>(o + 3 * 256) = a3;
  *reinterpret_cast<float4*>(o + 4 * 256) = a4;
  *reinterpret_cast<float4*>(o + 5 * 256) = a5;
  *reinterpret_cast<float4*>(o + 6 * 256) = a6;
  *reinterpret_cast<float4*>(o + 7 * 256) = a7;
}

// ---------------------------------------------------------------- k_reduce
// U[b,kd] = sum_c pU[(b*nchunk+c)][kd]
__global__ __launch_bounds__(256) void k_reduce(const float* __restrict__ pU,
                                                float* __restrict__ U, int nchunk) {
  int e = blockIdx.x * 64 + (threadIdx.x & 63);
  int sub = threadIdx.x >> 6;              // 0..3
  int b = e >> 13;
  int kd = e & 8191;
  const float* p = pU + (size_t)b * nchunk * 8192 + kd;
  float acc = 0.f;
  for (int c = sub; c < nchunk; c += 4) acc += p[(size_t)c * 8192];
  __shared__ float red[256];
  red[threadIdx.x] = acc;
  __syncthreads();
  if (threadIdx.x < 64)
    U[e] = (red[threadIdx.x] + red[threadIdx.x + 64]) +
           (red[threadIdx.x + 128] + red[threadIdx.x + 192]);
}

// ---------------------------------------------------------------- k_project
__global__ __launch_bounds__(256) void k_project(
    const float* __restrict__ U, const float* __restrict__ pS,
    const float* __restrict__ Wq, const float* __restrict__ bq,
    const float* __restrict__ Wk, const float* __restrict__ bk,
    const float* __restrict__ Wv, const float* __restrict__ bv,
    const float* __restrict__ ev, const float* __restrict__ bb,
    const float* __restrict__ fw,
    float* __restrict__ Qfg, float* __restrict__ Kfg, float* __restrict__ Vfg) {
  int blk = blockIdx.x;                    // b*32 + k
  int k = blk & 31;
  int t = threadIdx.x;
  __shared__ __align__(16) float u[256];
  __shared__ float red[256];
  u[t] = U[(size_t)blk * 256 + t];
  red[t] = pS[t * 32 + k];
  __syncthreads();
#pragma unroll
  for (int off = 128; off > 0; off >>= 1) {
    if (t < off) red[t] += red[t + off];
    __syncthreads();
  }
  float sk = red[0];

  // filter response — FP64 to match numpy ref branch semantics
  float mnf = ev[0], mxf = ev[0];
#pragma unroll
  for (int i = 1; i < 32; ++i) { float v = ev[i]; mnf = fminf(mnf, v); mxf = fmaxf(mxf, v); }
  double mn = (double)mnf, mx = (double)mxf;
  double lam = ((double)ev[k] - mn) / (mx - mn + 1e-8);
  int h = t >> 5;
  float g = 0.f;
#pragma unroll
  for (int i = 0; i < 3; ++i) {
    double lo = (double)bb[h * 4 + i], hi = (double)bb[h * 4 + i + 1];
    if (lam >= lo && lam < hi) g = fw[(h * 3 + i) * 32 + k];
  }

  const float4* u4 = reinterpret_cast<const float4*>(u);
  const float4* wq4 = reinterpret_cast<const float4*>(Wq) + (size_t)t * 64;
  const float4* wk4 = reinterpret_cast<const float4*>(Wk) + (size_t)t * 64;
  const float4* wv4 = reinterpret_cast<const float4*>(Wv) + (size_t)t * 64;
  float aq = 0.f, ak = 0.f, av = 0.f;
#pragma unroll 4
  for (int j = 0; j < 64; ++j) {
    float4 uv = u4[j];
    float4 q = wq4[j], kk = wk4[j], vv = wv4[j];
    aq = fmaf(uv.x, q.x, aq);  aq = fmaf(uv.y, q.y, aq);
    aq = fmaf(uv.z, q.z, aq);  aq = fmaf(uv.w, q.w, aq);
    ak = fmaf(uv.x, kk.x, ak); ak = fmaf(uv.y, kk.y, ak);
    ak = fmaf(uv.z, kk.z, ak); ak = fmaf(uv.w, kk.w, ak);
    av = fmaf(uv.x, vv.x, av); av = fmaf(uv.y, vv.y, av);
    av = fmaf(uv.z, vv.z, av); av = fmaf(uv.w, vv.w, av);
  }
  Qfg[(size_t)blk * 256 + t] = (aq + bq[t] * sk) * g;
  Kfg[(size_t)blk * 256 + t] = (ak + bk[t] * sk) * g;
  Vfg[(size_t)blk * 256 + t] = (av + bv[t] * sk) * g;
}

// ---------------------------------------------------------------- k_attn
__global__ __launch_bounds__(1024) void k_attn(const float* __restrict__ Qfg,
                                               const float* __restrict__ Kfg,
                                               const float* __restrict__ Vfg,
                                               float* __restrict__ of) {
  int blk = blockIdx.x;                    // b*8 + h
  int b = blk >> 3, h = blk & 7;
  int tid = threadIdx.x;
  int row = tid >> 5, col = tid & 31;
  __shared__ float Q[32][33], Kt[32][33], V[32][33], A[32][33];
  size_t base = (size_t)b * 32 * 256 + h * 32;
  Q[row][col]  = Qfg[base + row * 256 + col];
  Kt[row][col] = Kfg[base + row * 256 + col];
  V[row][col]  = Vfg[base + row * 256 + col];
  __syncthreads();
  float sc = 0.f;
#pragma unroll
  for (int d0 = 0; d0 < 32; ++d0) sc = fmaf(Q[row][d0], Kt[col][d0], sc);
  sc *= 0.17677669529663687f;              // 1/sqrt(32)
  float m = sc;
#pragma unroll
  for (int o = 16; o > 0; o >>= 1) m = fmaxf(m, __shfl_xor(m, o, 32));
  float p = expf(sc - m);
  float su = p;
#pragma unroll
  for (int o = 16; o > 0; o >>= 1) su += __shfl_xor(su, o, 32);
  A[row][col] = p / su;
  __syncthreads();
  float o_ = 0.f;
#pragma unroll
  for (int l = 0; l < 32; ++l) o_ = fmaf(A[row][l], V[l][col], o_);
  of[base + row * 256 + col] = o_;
}

// ---------------------------------------------------------------- k_expand
// out[b,n,d] = sum_k E[n,k] * of[b,k,d]. Thread t owns d=t, computes BOTH b
// (of in 32 float2 regs). E tile staged in LDS, broadcast ds_read per row.
// Writes: wave = 256B, block = 1KB per b per row (coalesced).
__global__ __launch_bounds__(256) void k_expand(const float* __restrict__ E,
                                                const float* __restrict__ of,
                                                float* __restrict__ out,
                                                int N, int rows) {
  int blk = blockIdx.x;
  int n0 = blk * rows;
  int n1 = n0 + rows; if (n1 > N) n1 = N;
  int nrows = n1 - n0;
  int t = threadIdx.x;

  // of regs: fk = {of[b=0][k][t], of[b=1][k][t]}   (B == 2)
  const float* ofb = of + t;
#define LDF(i) float2 f##i = make_float2(ofb[(i) * 256], ofb[8192 + (i) * 256]);
  LDF(0)  LDF(1)  LDF(2)  LDF(3)  LDF(4)  LDF(5)  LDF(6)  LDF(7)
  LDF(8)  LDF(9)  LDF(10) LDF(11) LDF(12) LDF(13) LDF(14) LDF(15)
  LDF(16) LDF(17) LDF(18) LDF(19) LDF(20) LDF(21) LDF(22) LDF(23)
  LDF(24) LDF(25) LDF(26) LDF(27) LDF(28) LDF(29) LDF(30) LDF(31)
#undef LDF

  // stage E tile [nrows][32] -> LDS (rows <= 64)
  __shared__ __align__(16) float Elds[64 * 32];
  {
    const float4* Esrc = reinterpret_cast<const float4*>(E + (size_t)n0 * 32);
    float4* Edst = reinterpret_cast<float4*>(Elds);
    int nf4 = nrows * 8;
    for (int i = t; i < nf4; i += 256) Edst[i] = Esrc[i];
  }
  __syncthreads();

  float* o0 = out + t;
  float* o1 = out + (size_t)N * D + t;

#define EXP2(s, fk) { acc0 = fmaf(s, fk.x, acc0); acc1 = fmaf(s, fk.y, acc1); }
  for (int i = 0; i < nrows; ++i) {
    const float4* er = reinterpret_cast<const float4*>(Elds + i * 32);
    float4 e0 = er[0], e1 = er[1], e2 = er[2], e3 = er[3];
    float4 e4 = er[4], e5 = er[5], e6 = er[6], e7 = er[7];
    float acc0 = 0.f, acc1 = 0.f;
    EXP2(e0.x, f0)  EXP2(e0.y, f1)  EXP2(e0.z, f2)  EXP2(e0.w, f3)
    EXP2(e1.x, f4)  EXP2(e1.y, f5)  EXP2(e1.z, f6)  EXP2(e1.w, f7)
    EXP2(e2.x, f8)  EXP2(e2.y, f9)  EXP2(e2.z, f10) EXP2(e2.w, f11)
    EXP2(e3.x, f12) EXP2(e3.y, f13) EXP2(e3.z, f14) EXP2(e3.w, f15)
    EXP2(e4.x, f16) EXP2(e4.y, f17) EXP2(e4.z, f18) EXP2(e4.w, f19)
    EXP2(e5.x, f20) EXP2(e5.y, f21) EXP2(e5.z, f22) EXP2(e5.w, f23)
    EXP2(e6.x, f24) EXP2(e6.y, f25) EXP2(e6.z, f26) EXP2(e6.w, f27)
    EXP2(e7.x, f28) EXP2(e7.y, f29) EXP2(e7.z, f30) EXP2(e7.w, f31)
    size_t roff = (size_t)(n0 + i) * D;
    o0[roff] = acc0;
    o1[roff] = acc1;
  }
#undef EXP2
}

// ---------------------------------------------------------------- launch
extern "C" void kernel_launch(void* const* d_in, const int* in_sizes, int n_in,
                              void* d_out, int out_size, void* d_ws, size_t ws_size,
                              hipStream_t stream) {
  const float* x  = (const float*)d_in[0];
  const float* E  = (const float*)d_in[1];
  const float* ev = (const float*)d_in[2];
  const float* Wq = (const float*)d_in[3];
  const float* bq = (const float*)d_in[4];
  const float* Wk = (const float*)d_in[5];
  const float* bk = (const float*)d_in[6];
  const float* Wv = (const float*)d_in[7];
  const float* bv = (const float*)d_in[8];
  const float* bb = (const float*)d_in[9];
  const float* fw = (const float*)d_in[10];
  float* out = (float*)d_out;
  float* ws  = (float*)d_ws;

  const int N = in_sizes[1] / 32;          // 50000
  const int B = in_sizes[0] / (N * 256);   // 2

  // workspace layout (floats)
  float* U   = ws;                         // B*32*256 = 16384
  float* Qfg = ws + 16384;
  float* Kfg = ws + 32768;
  float* Vfg = ws + 49152;
  float* of  = ws + 65536;
  float* pS  = ws + 81920;                 // 256*32 = 8192
  float* pU  = ws + 90112;                 // B*nchunk*8192 floats

  // nchunk = 512 -> grid 1024 (4 blocks/CU), pU 33.9 MB; fallback 256 (17 MB,
  // known to fit from round 5). rpc <= 196 keeps the 25KB LDS tile valid.
  int nchunk = 512;
  if ((90112 + (size_t)B * nchunk * 8192) * sizeof(float) > ws_size) nchunk = 256;
  int rpc = (N + nchunk - 1) / nchunk;

  k_colsum<<<256, 256, 0, stream>>>(E, pS, N);
  k_partial<<<B * nchunk, 256, 0, stream>>>(x, E, pU, N, nchunk, rpc);
  k_reduce<<<B * 128, 256, 0, stream>>>(pU, U, nchunk);
  k_project<<<B * 32, 256, 0, stream>>>(U, pS, Wq, bq, Wk, bk, Wv, bv,
                                        ev, bb, fw, Qfg, Kfg, Vfg);
  k_attn<<<B * 8, 1024, 0, stream>>>(Qfg, Kfg, Vfg, of);
  int rows = 64;
  int nbr = (N + rows - 1) / rows;
  k_expand<<<nbr, 256, 0, stream>>>(E, of, out, N, rows);
}

// Round 7
// 118.020 us; speedup vs baseline: 1.9997x; 1.2272x over previous
//
#include <hip/hip_runtime.h>
#include <hip/hip_bf16.h>

// Spectral attention: B=2, N=50000, D=256, H=8, Dh=32, K_EIG=32, NUM_BANDS=3
// Key identity: Qf = E^T (x Wq^T + bq) = (E^T x) Wq^T + s * bq, s[k] = sum_n E[n,k]
// N-sized work: U = E^T x (read x once) and out = E @ out_freq (write out once).
// Lessons: r2 = per-thread arrays spill (named regs only); r3 = no redundant
// HBM x reads; r4 = >=4 blocks/CU; r5 = stage E in LDS; r6 = 2-deep prefetch
// is NOT enough (latency-bound at VALUBusy 18%) -> 8-deep x pipeline, MLP in
// the reduce, no grid tails.

constexpr int D = 256;   // d_model

// ---------------------------------------------------------------- k_colsum
__global__ __launch_bounds__(256) void k_colsum(const float* __restrict__ E,
                                                float* __restrict__ pS, int N) {
  int k = threadIdx.x & 31;
  int rg = threadIdx.x >> 5;
  int rs = (N + 255) >> 8;
  int n0 = blockIdx.x * rs;
  int n1 = n0 + rs; if (n1 > N) n1 = N;
  float acc = 0.f;
  for (int n = n0 + rg; n < n1; n += 8) acc += E[(size_t)n * 32 + k];
  __shared__ float red[256];
  red[threadIdx.x] = acc;
  __syncthreads();
  if (threadIdx.x < 32) {
    float t = red[threadIdx.x];
#pragma unroll
    for (int i = 1; i < 8; ++i) t += red[i * 32 + threadIdx.x];
    pS[blockIdx.x * 32 + threadIdx.x] = t;
  }
}

// ---------------------------------------------------------------- k_partial
// grid = B*nchunk. Wave w owns k-octet [8w,8w+8); lane owns d-quad (float4 x).
// E tile in LDS (broadcast reads). 8-deep x prefetch in named regs, 8 rows/iter.
__global__ __launch_bounds__(256) void k_partial(const float* __restrict__ x,
                                                 const float* __restrict__ E,
                                                 float* __restrict__ pU,
                                                 int N, int nchunk, int rpc) {
  int blk = blockIdx.x;                    // b*nchunk + c
  int c = blk % nchunk;
  int b = blk / nchunk;
  int t = threadIdx.x;
  int w = t >> 6;                          // wave id -> k-octet
  int lane = t & 63;
  int n0 = c * rpc;
  int n1 = n0 + rpc; if (n1 > N) n1 = N;
  int nrows = n1 - n0;

  float4 a0 = {0,0,0,0}, a1 = {0,0,0,0}, a2 = {0,0,0,0}, a3 = {0,0,0,0};
  float4 a4 = {0,0,0,0}, a5 = {0,0,0,0}, a6 = {0,0,0,0}, a7 = {0,0,0,0};

  __shared__ __align__(16) float Elds[200 * 32];   // rpc <= 196

  if (nrows > 0) {
    {  // stage E tile [nrows][32]
      const float4* Esrc = reinterpret_cast<const float4*>(E + (size_t)n0 * 32);
      float4* Edst = reinterpret_cast<float4*>(Elds);
      int nf4 = nrows * 8;
      for (int i = t; i < nf4; i += 256) Edst[i] = Esrc[i];
    }
    __syncthreads();

    const float* xb = x + (size_t)b * N * D + 4 * lane;
#define XLD(r) (*reinterpret_cast<const float4*>(xb + (size_t)(n0 + (r)) * D))
#define XLDC(r) XLD((r) < nrows ? (r) : nrows - 1)

    float4 p0 = XLDC(0), p1 = XLDC(1), p2 = XLDC(2), p3 = XLDC(3);
    float4 p4 = XLDC(4), p5 = XLDC(5), p6 = XLDC(6), p7 = XLDC(7);

#define FMAROW(eA, eB, xq)                                                     \
  a0.x=fmaf(eA.x,xq.x,a0.x); a0.y=fmaf(eA.x,xq.y,a0.y);                        \
  a0.z=fmaf(eA.x,xq.z,a0.z); a0.w=fmaf(eA.x,xq.w,a0.w);                        \
  a1.x=fmaf(eA.y,xq.x,a1.x); a1.y=fmaf(eA.y,xq.y,a1.y);                        \
  a1.z=fmaf(eA.y,xq.z,a1.z); a1.w=fmaf(eA.y,xq.w,a1.w);                        \
  a2.x=fmaf(eA.z,xq.x,a2.x); a2.y=fmaf(eA.z,xq.y,a2.y);                        \
  a2.z=fmaf(eA.z,xq.z,a2.z); a2.w=fmaf(eA.z,xq.w,a2.w);                        \
  a3.x=fmaf(eA.w,xq.x,a3.x); a3.y=fmaf(eA.w,xq.y,a3.y);                        \
  a3.z=fmaf(eA.w,xq.z,a3.z); a3.w=fmaf(eA.w,xq.w,a3.w);                        \
  a4.x=fmaf(eB.x,xq.x,a4.x); a4.y=fmaf(eB.x,xq.y,a4.y);                        \
  a4.z=fmaf(eB.x,xq.z,a4.z); a4.w=fmaf(eB.x,xq.w,a4.w);                        \
  a5.x=fmaf(eB.y,xq.x,a5.x); a5.y=fmaf(eB.y,xq.y,a5.y);                        \
  a5.z=fmaf(eB.y,xq.z,a5.z); a5.w=fmaf(eB.y,xq.w,a5.w);                        \
  a6.x=fmaf(eB.z,xq.x,a6.x); a6.y=fmaf(eB.z,xq.y,a6.y);                        \
  a6.z=fmaf(eB.z,xq.z,a6.z); a6.w=fmaf(eB.z,xq.w,a6.w);                        \
  a7.x=fmaf(eB.w,xq.x,a7.x); a7.y=fmaf(eB.w,xq.y,a7.y);                        \
  a7.z=fmaf(eB.w,xq.z,a7.z); a7.w=fmaf(eB.w,xq.w,a7.w);

#define ROW4(base, q0, q1, q2, q3) {                                           \
    const float* eb = Elds + (base) * 32 + 8 * w;                              \
    float4 eA0 = *(const float4*)(eb);      float4 eB0 = *(const float4*)(eb+4);   \
    float4 eA1 = *(const float4*)(eb+32);   float4 eB1 = *(const float4*)(eb+36);  \
    float4 eA2 = *(const float4*)(eb+64);   float4 eB2 = *(const float4*)(eb+68);  \
    float4 eA3 = *(const float4*)(eb+96);   float4 eB3 = *(const float4*)(eb+100); \
    FMAROW(eA0, eB0, q0) FMAROW(eA1, eB1, q1)                                  \
    FMAROW(eA2, eB2, q2) FMAROW(eA3, eB3, q3) }

#define ROW1(r, q) {                                                           \
    const float* eb = Elds + (r) * 32 + 8 * w;                                 \
    float4 eA = *(const float4*)(eb); float4 eB = *(const float4*)(eb + 4);    \
    FMAROW(eA, eB, q) }

    int i = 0;
#pragma unroll 1
    for (; i + 8 <= nrows; i += 8) {
      ROW4(i, p0, p1, p2, p3)
      p0 = XLDC(i + 8);  p1 = XLDC(i + 9);  p2 = XLDC(i + 10); p3 = XLDC(i + 11);
      ROW4(i + 4, p4, p5, p6, p7)
      p4 = XLDC(i + 12); p5 = XLDC(i + 13); p6 = XLDC(i + 14); p7 = XLDC(i + 15);
    }
    int rem = nrows - i;                   // 0..7, rows i..i+rem-1 are in p0..p6
    if (rem > 0) ROW1(i + 0, p0)
    if (rem > 1) ROW1(i + 1, p1)
    if (rem > 2) ROW1(i + 2, p2)
    if (rem > 3) ROW1(i + 3, p3)
    if (rem > 4) ROW1(i + 4, p4)
    if (rem > 5) ROW1(i + 5, p5)
    if (rem > 6) ROW1(i + 6, p6)
#undef ROW1
#undef ROW4
#undef FMAROW
#undef XLDC
#undef XLD
  }

  float* o = pU + (size_t)blk * 8192 + (size_t)(8 * w) * 256 + 4 * lane;
  *reinterpret_cast<float4*>(o + 0 * 256) = a0;
  *reinterpret_cast<float4*>(o + 1 * 256) = a1;
  *reinterpret_cast<float4*>(o + 2 * 256) = a2;
  *reinterpret_cast<float4*>(o + 3 * 256) = a3;
  *reinterpret_cast<float4*>(o + 4 * 256) = a4;
  *reinterpret_cast<float4*>(o + 5 * 256) = a5;
  *reinterpret_cast<float4*>(o + 6 * 256) = a6;
  *reinterpret_cast<float4*>(o + 7 * 256) = a7;
}

// ---------------------------------------------------------------- k_reduce
// 512 blocks; block covers 32 kd-elements; 8 sub-groups x 4 indep accumulators.
__global__ __launch_bounds__(256) void k_reduce(const float* __restrict__ pU,
                                                float* __restrict__ U, int nchunk) {
  int e = blockIdx.x * 32 + (threadIdx.x & 31);
  int sub = threadIdx.x >> 5;              // 0..7
  int b = e >> 13;
  int kd = e & 8191;
  const float* p = pU + (size_t)b * nchunk * 8192 + kd;
  float a0 = 0.f, a1 = 0.f, a2 = 0.f, a3 = 0.f;
  int c = sub;
#pragma unroll 1
  for (; c + 24 < nchunk; c += 32) {
    a0 += p[(size_t)c * 8192];
    a1 += p[(size_t)(c + 8) * 8192];
    a2 += p[(size_t)(c + 16) * 8192];
    a3 += p[(size_t)(c + 24) * 8192];
  }
  for (; c < nchunk; c += 8) a0 += p[(size_t)c * 8192];
  __shared__ float red[256];
  red[threadIdx.x] = (a0 + a1) + (a2 + a3);
  __syncthreads();
  if (threadIdx.x < 32) {
    float s = red[threadIdx.x];
#pragma unroll
    for (int i = 1; i < 8; ++i) s += red[i * 32 + threadIdx.x];
    U[e] = s;
  }
}

// ---------------------------------------------------------------- k_project
__global__ __launch_bounds__(256) void k_project(
    const float* __restrict__ U, const float* __restrict__ pS,
    const float* __restrict__ Wq, const float* __restrict__ bq,
    const float* __restrict__ Wk, const float* __restrict__ bk,
    const float* __restrict__ Wv, const float* __restrict__ bv,
    const float* __restrict__ ev, const float* __restrict__ bb,
    const float* __restrict__ fw,
    float* __restrict__ Qfg, float* __restrict__ Kfg, float* __restrict__ Vfg) {
  int blk = blockIdx.x;                    // b*32 + k
  int k = blk & 31;
  int t = threadIdx.x;
  __shared__ __align__(16) float u[256];
  __shared__ float red[256];
  u[t] = U[(size_t)blk * 256 + t];
  red[t] = pS[t * 32 + k];
  __syncthreads();
#pragma unroll
  for (int off = 128; off > 0; off >>= 1) {
    if (t < off) red[t] += red[t + off];
    __syncthreads();
  }
  float sk = red[0];

  // filter response — FP64 to match numpy ref branch semantics
  float mnf = ev[0], mxf = ev[0];
#pragma unroll
  for (int i = 1; i < 32; ++i) { float v = ev[i]; mnf = fminf(mnf, v); mxf = fmaxf(mxf, v); }
  double mn = (double)mnf, mx = (double)mxf;
  double lam = ((double)ev[k] - mn) / (mx - mn + 1e-8);
  int h = t >> 5;
  float g = 0.f;
#pragma unroll
  for (int i = 0; i < 3; ++i) {
    double lo = (double)bb[h * 4 + i], hi = (double)bb[h * 4 + i + 1];
    if (lam >= lo && lam < hi) g = fw[(h * 3 + i) * 32 + k];
  }

  const float4* u4 = reinterpret_cast<const float4*>(u);
  const float4* wq4 = reinterpret_cast<const float4*>(Wq) + (size_t)t * 64;
  const float4* wk4 = reinterpret_cast<const float4*>(Wk) + (size_t)t * 64;
  const float4* wv4 = reinterpret_cast<const float4*>(Wv) + (size_t)t * 64;
  float aq = 0.f, ak = 0.f, av = 0.f;
#pragma unroll 4
  for (int j = 0; j < 64; ++j) {
    float4 uv = u4[j];
    float4 q = wq4[j], kk = wk4[j], vv = wv4[j];
    aq = fmaf(uv.x, q.x, aq);  aq = fmaf(uv.y, q.y, aq);
    aq = fmaf(uv.z, q.z, aq);  aq = fmaf(uv.w, q.w, aq);
    ak = fmaf(uv.x, kk.x, ak); ak = fmaf(uv.y, kk.y, ak);
    ak = fmaf(uv.z, kk.z, ak); ak = fmaf(uv.w, kk.w, ak);
    av = fmaf(uv.x, vv.x, av); av = fmaf(uv.y, vv.y, av);
    av = fmaf(uv.z, vv.z, av); av = fmaf(uv.w, vv.w, av);
  }
  Qfg[(size_t)blk * 256 + t] = (aq + bq[t] * sk) * g;
  Kfg[(size_t)blk * 256 + t] = (ak + bk[t] * sk) * g;
  Vfg[(size_t)blk * 256 + t] = (av + bv[t] * sk) * g;
}

// ---------------------------------------------------------------- k_attn
__global__ __launch_bounds__(1024) void k_attn(const float* __restrict__ Qfg,
                                               const float* __restrict__ Kfg,
                                               const float* __restrict__ Vfg,
                                               float* __restrict__ of) {
  int blk = blockIdx.x;                    // b*8 + h
  int b = blk >> 3, h = blk & 7;
  int tid = threadIdx.x;
  int row = tid >> 5, col = tid & 31;
  __shared__ float Q[32][33], Kt[32][33], V[32][33], A[32][33];
  size_t base = (size_t)b * 32 * 256 + h * 32;
  Q[row][col]  = Qfg[base + row * 256 + col];
  Kt[row][col] = Kfg[base + row * 256 + col];
  V[row][col]  = Vfg[base + row * 256 + col];
  __syncthreads();
  float sc = 0.f;
#pragma unroll
  for (int d0 = 0; d0 < 32; ++d0) sc = fmaf(Q[row][d0], Kt[col][d0], sc);
  sc *= 0.17677669529663687f;              // 1/sqrt(32)
  float m = sc;
#pragma unroll
  for (int o = 16; o > 0; o >>= 1) m = fmaxf(m, __shfl_xor(m, o, 32));
  float p = expf(sc - m);
  float su = p;
#pragma unroll
  for (int o = 16; o > 0; o >>= 1) su += __shfl_xor(su, o, 32);
  A[row][col] = p / su;
  __syncthreads();
  float o_ = 0.f;
#pragma unroll
  for (int l = 0; l < 32; ++l) o_ = fmaf(A[row][l], V[l][col], o_);
  of[base + row * 256 + col] = o_;
}

// ---------------------------------------------------------------- k_expand
// out[b,n,d] = sum_k E[n,k] * of[b,k,d]. Thread owns d=t, computes BOTH b
// (of in 32 float2 regs). E tile in LDS, broadcast ds_read per row.
__global__ __launch_bounds__(256) void k_expand(const float* __restrict__ E,
                                                const float* __restrict__ of,
                                                float* __restrict__ out,
                                                int N, int rows) {
  int n0 = blockIdx.x * rows;
  int n1 = n0 + rows; if (n1 > N) n1 = N;
  int nrows = n1 - n0;
  if (nrows <= 0) return;
  int t = threadIdx.x;

  const float* ofb = of + t;               // fk = {of[0][k][t], of[1][k][t]}
#define LDF(i) float2 f##i = make_float2(ofb[(i) * 256], ofb[8192 + (i) * 256]);
  LDF(0)  LDF(1)  LDF(2)  LDF(3)  LDF(4)  LDF(5)  LDF(6)  LDF(7)
  LDF(8)  LDF(9)  LDF(10) LDF(11) LDF(12) LDF(13) LDF(14) LDF(15)
  LDF(16) LDF(17) LDF(18) LDF(19) LDF(20) LDF(21) LDF(22) LDF(23)
  LDF(24) LDF(25) LDF(26) LDF(27) LDF(28) LDF(29) LDF(30) LDF(31)
#undef LDF

  __shared__ __align__(16) float Elds[50 * 32];    // rows <= 50
  {
    const float4* Esrc = reinterpret_cast<const float4*>(E + (size_t)n0 * 32);
    float4* Edst = reinterpret_cast<float4*>(Elds);
    int nf4 = nrows * 8;
    for (int i = t; i < nf4; i += 256) Edst[i] = Esrc[i];
  }
  __syncthreads();

  float* o0 = out + t;
  float* o1 = out + (size_t)N * D + t;

#define EXP2(s, fk) { acc0 = fmaf(s, fk.x, acc0); acc1 = fmaf(s, fk.y, acc1); }
#pragma unroll 1
  for (int i = 0; i < nrows; ++i) {
    const float4* er = reinterpret_cast<const float4*>(Elds + i * 32);
    float4 e0 = er[0], e1 = er[1], e2 = er[2], e3 = er[3];
    float4 e4 = er[4], e5 = er[5], e6 = er[6], e7 = er[7];
    float acc0 = 0.f, acc1 = 0.f;
    EXP2(e0.x, f0)  EXP2(e0.y, f1)  EXP2(e0.z, f2)  EXP2(e0.w, f3)
    EXP2(e1.x, f4)  EXP2(e1.y, f5)  EXP2(e1.z, f6)  EXP2(e1.w, f7)
    EXP2(e2.x, f8)  EXP2(e2.y, f9)  EXP2(e2.z, f10) EXP2(e2.w, f11)
    EXP2(e3.x, f12) EXP2(e3.y, f13) EXP2(e3.z, f14) EXP2(e3.w, f15)
    EXP2(e4.x, f16) EXP2(e4.y, f17) EXP2(e4.z, f18) EXP2(e4.w, f19)
    EXP2(e5.x, f20) EXP2(e5.y, f21) EXP2(e5.z, f22) EXP2(e5.w, f23)
    EXP2(e6.x, f24) EXP2(e6.y, f25) EXP2(e6.z, f26) EXP2(e6.w, f27)
    EXP2(e7.x, f28) EXP2(e7.y, f29) EXP2(e7.z, f30) EXP2(e7.w, f31)
    size_t roff = (size_t)(n0 + i) * D;
    o0[roff] = acc0;
    o1[roff] = acc1;
  }
#undef EXP2
}

// ---------------------------------------------------------------- launch
extern "C" void kernel_launch(void* const* d_in, const int* in_sizes, int n_in,
                              void* d_out, int out_size, void* d_ws, size_t ws_size,
                              hipStream_t stream) {
  const float* x  = (const float*)d_in[0];
  const float* E  = (const float*)d_in[1];
  const float* ev = (const float*)d_in[2];
  const float* Wq = (const float*)d_in[3];
  const float* bq = (const float*)d_in[4];
  const float* Wk = (const float*)d_in[5];
  const float* bk = (const float*)d_in[6];
  const float* Wv = (const float*)d_in[7];
  const float* bv = (const float*)d_in[8];
  const float* bb = (const float*)d_in[9];
  const float* fw = (const float*)d_in[10];
  float* out = (float*)d_out;
  float* ws  = (float*)d_ws;

  const int N = in_sizes[1] / 32;          // 50000
  const int B = in_sizes[0] / (N * 256);   // 2

  // workspace layout (floats)
  float* U   = ws;                         // B*32*256 = 16384
  float* Qfg = ws + 16384;
  float* Kfg = ws + 32768;
  float* Vfg = ws + 49152;
  float* of  = ws + 65536;
  float* pS  = ws + 81920;                 // 256*32 = 8192
  float* pU  = ws + 90112;                 // B*nchunk*8192 floats

  // nchunk = 512 -> grid 1024 (4 blocks/CU), pU 33.6 MB (fit in r6).
  // Fallback 256 keeps rpc <= 196 (Elds sized 200 rows).
  int nchunk = 512;
  if ((90112 + (size_t)B * nchunk * 8192) * sizeof(float) > ws_size) nchunk = 256;
  int rpc = (N + nchunk - 1) / nchunk;

  k_colsum<<<256, 256, 0, stream>>>(E, pS, N);
  k_partial<<<B * nchunk, 256, 0, stream>>>(x, E, pU, N, nchunk, rpc);
  k_reduce<<<B * 8192 / 32, 256, 0, stream>>>(pU, U, nchunk);
  k_project<<<B * 32, 256, 0, stream>>>(U, pS, Wq, bq, Wk, bk, Wv, bv,
                                        ev, bb, fw, Qfg, Kfg, Vfg);
  k_attn<<<B * 8, 1024, 0, stream>>>(Qfg, Kfg, Vfg, of);
  int rows = 50;
  int nbr = (N + rows - 1) / rows;
  k_expand<<<nbr, 256, 0, stream>>>(E, of, out, N, rows);
}